// Round 1
// baseline (303.789 us; speedup 1.0000x reference)
//
#include <hip/hip_runtime.h>
#include <math.h>

#define NN 4
#define TMAX 20
#define EPS 1e-6f
#define POST_MULT 2.0f

// Native vector type usable with __builtin_nontemporal_store (HIP's float4 is
// a class and is rejected by the builtin).
typedef float vfloat4 __attribute__((ext_vector_type(4)));

// ---------------------------------------------------------------------------
// Fused kernel: one block per t.
//   Phase 1 (lanes 0..15 of wave 0): compute the 24 per-t coefficients via
//     intra-16-lane shuffle Sinkhorn (identical math to the previous
//     coeff_kernel) and stash them in 96 B of LDS. Other waves wait at one
//     barrier; the VALU cost hides under the memory stream of co-resident
//     blocks (~8 blocks/CU).
//   Phase 2 (all 256 threads): pure streaming, identical to the previous
//     stream_kernel, but coefficients come from LDS instead of a global
//     round-trip. This removes one kernel dispatch + graph node and the
//     (T,24) coeffs write/read.
// LDS layout: [0..3]=h_pre, [4..7]=h_post*POST_MULT, [8..23]=h_res flat
// (flat = i*4+j, i.e. h_res[i][j]).
// ---------------------------------------------------------------------------
__global__ __launch_bounds__(256) void fused_kernel(
    const float* __restrict__ x,          // (T, 4, C)
    const float* __restrict__ f_out,      // (T, C)
    const float* __restrict__ mix,        // (T, 24)
    const float* __restrict__ invr,       // (T,)
    const float* __restrict__ alpha_pre,  // (1,)
    const float* __restrict__ alpha_post, // (1,)
    const float* __restrict__ alpha_res,  // (1,)
    const float* __restrict__ bias,       // (24,)
    float* __restrict__ y_pre,            // (T, C)
    float* __restrict__ out,              // (T, 4, C)
    int C)
{
    __shared__ float sm[24];

    const int t   = blockIdx.x;
    const int tid = threadIdx.x;

    // --- Phase 1: coefficients (lanes 0..15 of wave 0 only) ---
    if (tid < 16) {
        const int lane = tid;              // flat index i*4+j
        const float ir = invr[t];

        // Sinkhorn on the 4x4
        float r = mix[t * 24 + 8 + lane] * ir * alpha_res[0] + bias[8 + lane];
        // row max over j: lanes differing in bits 0,1
        float m = r;
        m = fmaxf(m, __shfl_xor(m, 1));
        m = fmaxf(m, __shfl_xor(m, 2));
        r = __expf(r - m);
        #pragma unroll
        for (int it = 0; it < TMAX; ++it) {
            float rs = r;                   // row sum (over j)
            rs += __shfl_xor(rs, 1);
            rs += __shfl_xor(rs, 2);
            r = r / (rs + EPS);
            float cs = r;                   // col sum (over i)
            cs += __shfl_xor(cs, 4);
            cs += __shfl_xor(cs, 8);
            r = r / (cs + EPS);
        }
        sm[8 + lane] = r;

        // gates: lanes 0..7
        if (lane < 8) {
            const float a = (lane < NN) ? alpha_pre[0] : alpha_post[0];
            const float z = mix[t * 24 + lane] * ir * a + bias[lane];
            float sg = 1.0f / (1.0f + __expf(-z));
            if (lane >= NN) sg *= POST_MULT;
            sm[lane] = sg;
        }
    }
    __syncthreads();

    // --- Phase 2: streaming (all threads) ---
    const float hp0 = sm[0], hp1 = sm[1], hp2 = sm[2], hp3 = sm[3];
    const float hq0 = sm[4], hq1 = sm[5], hq2 = sm[6], hq3 = sm[7];
    float hr[NN][NN];  // hr[j][i] = h_res[j][i] = sm[8 + j*4 + i]
    #pragma unroll
    for (int j = 0; j < NN; ++j)
        #pragma unroll
        for (int i = 0; i < NN; ++i)
            hr[j][i] = sm[8 + j * 4 + i];

    const int NV = C >> 2;
    const vfloat4* xv4 = (const vfloat4*)(x + (size_t)t * NN * C);
    const vfloat4* fv4 = (const vfloat4*)(f_out + (size_t)t * C);
    vfloat4* yp4 = (vfloat4*)(y_pre + (size_t)t * C);
    vfloat4* o4  = (vfloat4*)(out + (size_t)t * NN * C);

    for (int v = tid; v < NV; v += blockDim.x) {
        vfloat4 xv[NN];
        #pragma unroll
        for (int n = 0; n < NN; ++n) xv[n] = xv4[n * NV + v];
        const vfloat4 fv = fv4[v];

        // y_pre = sum_n h_pre[n] * x[n]
        vfloat4 yv = hp0 * xv[0] + hp1 * xv[1] + hp2 * xv[2] + hp3 * xv[3];
        __builtin_nontemporal_store(yv, &yp4[v]);

        // out[j] = sum_i hr[j][i] * x[i] + h_post[j] * f_out
        const float hq[NN] = {hq0, hq1, hq2, hq3};
        #pragma unroll
        for (int j = 0; j < NN; ++j) {
            vfloat4 ov = hq[j] * fv;
            #pragma unroll
            for (int i = 0; i < NN; ++i) ov += hr[j][i] * xv[i];
            __builtin_nontemporal_store(ov, &o4[j * NV + v]);
        }
    }
}

extern "C" void kernel_launch(void* const* d_in, const int* in_sizes, int n_in,
                              void* d_out, int out_size, void* d_ws, size_t ws_size,
                              hipStream_t stream) {
    const float* x          = (const float*)d_in[0];
    const float* f_out      = (const float*)d_in[1];
    const float* mix        = (const float*)d_in[2];
    const float* invr       = (const float*)d_in[3];
    const float* alpha_pre  = (const float*)d_in[4];
    const float* alpha_post = (const float*)d_in[5];
    const float* alpha_res  = (const float*)d_in[6];
    const float* bias       = (const float*)d_in[7];

    const int T = in_sizes[3];               // invr is (T,)
    const int C = in_sizes[1] / T;           // f_out is (T, C)

    float* y_pre = (float*)d_out;                   // (T, C)
    float* out   = (float*)d_out + (size_t)T * C;   // (T, N, C)
    (void)d_ws; (void)ws_size;                      // no workspace needed

    fused_kernel<<<T, 256, 0, stream>>>(x, f_out, mix, invr, alpha_pre,
                                        alpha_post, alpha_res, bias,
                                        y_pre, out, C);
}